// Round 4
// baseline (497.547 us; speedup 1.0000x reference)
//
#include <hip/hip_runtime.h>

#define CHW 262144   // C*H*W = 256*32*32
#define HWD 1024     // H*W
#define WLCAP 262144

typedef _Float16 v8h __attribute__((ext_vector_type(8)));
typedef _Float16 v4h __attribute__((ext_vector_type(4)));
typedef float    v4f __attribute__((ext_vector_type(4)));

// ws layout (float offsets)
static const unsigned OFF_ASQ  = 0;        // ||z_n||^2 [8192]
static const unsigned OFF_BSQ  = 8192;     // ||e_k||^2 [8192]
static const unsigned OFF_CNT  = 16384;    // counts (int, ZEROED) [8192]
static const unsigned OFF_SCAL = 24576;    // [0]=loss_sum [1]=sum(cs) (ZEROED) [8]
static const unsigned OFF_WCNT = 24584;    // worklist count (int, ZEROED) [8]
static const unsigned OFF_DW   = 24592;    // dw (ZEROED) [2097152]
static const unsigned OFF_FIN  = 2121744;  // final keys u64 [8192] (16384 floats)
static const unsigned OFF_WL   = 2138128;  // worklist u32 [262144]
static const unsigned OFF_BH   = 2400272;  // Bh fp16 [8192*256] (1048576 floats)
static const unsigned OFF_BM   = 3448848;  // Bm fp16
// end 4497424 floats = 18.0 MB (ws >= 21.1 MB proven in round 1)

#define GLL(g, l) __builtin_amdgcn_global_load_lds( \
    (const __attribute__((address_space(1))) void*)(g), \
    (__attribute__((address_space(3))) void*)(l), 16, 0, 0)

// ---- fused: ||z_n||^2 + sum(cs)  |  emb -> bsq + fp16 split ----
__global__ __launch_bounds__(256) void k_prep0(const float* __restrict__ z, const float* __restrict__ cs,
        const float* __restrict__ emb, float* __restrict__ asq, float* __restrict__ bsq,
        _Float16* __restrict__ Bh, _Float16* __restrict__ Bm, float* __restrict__ scal) {
    int bx = blockIdx.x;
    if (bx < 32) {
        // ||z_n||^2 — keep the exact sequential 256-chain (bits feed the argmin)
        int n = bx * 256 + threadIdx.x;
        const float* p = z + (size_t)(n >> 10) * CHW + (n & 1023);
        float s = 0.f;
        #pragma unroll 8
        for (int c = 0; c < 256; ++c) { float v = p[(size_t)c << 10]; s = fmaf(v, v, s); }
        asq[n] = s;
        // sum(cluster_size) — loose tolerance, atomic order OK
        float cv = cs[n];
        #pragma unroll
        for (int m = 1; m < 64; m <<= 1) cv += __shfl_xor(cv, m, 64);
        if ((threadIdx.x & 63) == 0) atomicAdd(scal + 1, cv);
    } else {
        int w = (bx - 32) * 4 + (threadIdx.x >> 6);
        int lane = threadIdx.x & 63;
        float4 v = *(const float4*)(emb + (size_t)w * 256 + lane * 4);
        float s = v.x * v.x;
        s = fmaf(v.y, v.y, s); s = fmaf(v.z, v.z, s); s = fmaf(v.w, v.w, s);
        #pragma unroll
        for (int m = 1; m < 64; m <<= 1) s += __shfl_xor(s, m, 64);
        if (lane == 0) bsq[w] = s;
        float e0 = v.x * 8192.0f, e1 = v.y * 8192.0f, e2 = v.z * 8192.0f, e3 = v.w * 8192.0f;
        _Float16 h0 = (_Float16)e0, h1 = (_Float16)e1, h2 = (_Float16)e2, h3 = (_Float16)e3;
        v4h hv = {h0, h1, h2, h3};
        v4h mv = {(_Float16)((e0 - (float)h0) * 2048.0f),
                  (_Float16)((e1 - (float)h1) * 2048.0f),
                  (_Float16)((e2 - (float)h2) * 2048.0f),
                  (_Float16)((e3 - (float)h3) * 2048.0f)};
        *(v4h*)(Bh + (size_t)w * 256 + lane * 4) = hv;
        *(v4h*)(Bm + (size_t)w * 256 + lane * 4) = mv;
    }
}

// ---- z [b][c][hw] -> Ah/Am [n][c] fp16 (transpose + split) ----
__global__ __launch_bounds__(256) void prep_z(const float* __restrict__ z,
        _Float16* __restrict__ Ah, _Float16* __restrict__ Am) {
    __shared__ float s[64][65];
    int hw0 = (blockIdx.x & 15) * 64;
    int c0  = ((blockIdx.x >> 4) & 3) * 64;
    int b   = blockIdx.x >> 6;
    int t = threadIdx.x;
    #pragma unroll
    for (int ii = 0; ii < 16; ++ii) {
        int e = t + ii * 256;
        int c = e >> 6, x = e & 63;
        s[c][x] = z[(size_t)b * CHW + (size_t)(c0 + c) * HWD + hw0 + x];
    }
    __syncthreads();
    int n = t & 63, cseg = (t >> 6) * 16;
    _Float16 hbuf[16], mbuf[16];
    #pragma unroll
    for (int j = 0; j < 16; ++j) {
        float v = s[cseg + j][n];
        _Float16 h = (_Float16)v;
        float r = v - (float)h;
        hbuf[j] = h;
        mbuf[j] = (_Float16)(r * 2048.0f);
    }
    size_t off = ((size_t)b * 1024 + hw0 + n) * 256 + c0 + cseg;
    *(v8h*)(Ah + off)     = *(v8h*)(hbuf);
    *(v8h*)(Ah + off + 8) = *(v8h*)(hbuf + 8);
    *(v8h*)(Am + off)     = *(v8h*)(mbuf);
    *(v8h*)(Am + off + 8) = *(v8h*)(mbuf + 8);
}

// ---- pass 1: hh-only 128x128 MFMA tiles, per-16-k-group packed min keys ----
__global__ __launch_bounds__(256) void k_pass1(
        const _Float16* __restrict__ Ah, const _Float16* __restrict__ Bh,
        const float* __restrict__ asq, const float* __restrict__ bsq,
        unsigned* __restrict__ tk0, unsigned* __restrict__ tk1) {
    __shared__ _Float16 lds[16384];  // 32 KB: 2 buf x (A 8KB + B 8KB), XOR-swizzled
    const int kt = blockIdx.x, nt = blockIdx.y;
    const int n0 = nt * 128, k0 = kt * 128;
    const int t = threadIdx.x;
    const int lane = t & 63, w = t >> 6;
    const int wrow = w >> 1, wcol = w & 1;
    const int lm = lane & 15, quad = lane >> 4;

    v4f acc[4][4];
    #pragma unroll
    for (int i = 0; i < 4; ++i)
        #pragma unroll
        for (int j = 0; j < 4; ++j) acc[i][j] = (v4f){0.f, 0.f, 0.f, 0.f};

    const int row0 = t >> 2;
    const int c40 = (t & 3) ^ ((row0 >> 1) & 3);
    const char* gA0 = (const char*)Ah + (size_t)(n0 + row0) * 512 + c40 * 16;
    const char* gB0 = (const char*)Bh + (size_t)(k0 + row0) * 512 + c40 * 16;

    int sa[4], sb[4];
    #pragma unroll
    for (int i = 0; i < 4; ++i) {
        int mr = wrow * 64 + i * 16 + lm;
        sa[i] = mr * 32 + ((quad ^ ((mr >> 1) & 3)) * 8);
        int nr = wcol * 64 + i * 16 + lm;
        sb[i] = 4096 + nr * 32 + ((quad ^ ((nr >> 1) & 3)) * 8);
    }

    auto stage = [&](int cb, int buf) {
        const size_t co = (size_t)cb * 64;
        _Float16* l0 = lds + buf * 8192 + t * 8;
        _Float16* l1 = l0 + 2048;
        GLL(gA0 + co,          l0);
        GLL(gA0 + co + 32768,  l1);
        GLL(gB0 + co,          l0 + 4096);
        GLL(gB0 + co + 32768,  l1 + 4096);
    };

    stage(0, 0);
    for (int cb = 0; cb < 8; ++cb) {
        __syncthreads();
        if (cb < 7) stage(cb + 1, (cb + 1) & 1);
        const _Float16* L = lds + (cb & 1) * 8192;
        v8h fa[4], fb[4];
        #pragma unroll
        for (int i = 0; i < 4; ++i) {
            fa[i] = *(const v8h*)(L + sa[i]);
            fb[i] = *(const v8h*)(L + sb[i]);
        }
        #pragma unroll
        for (int i = 0; i < 4; ++i)
            #pragma unroll
            for (int j = 0; j < 4; ++j)
                acc[i][j] = __builtin_amdgcn_mfma_f32_16x16x32_f16(fa[i], fb[j], acc[i][j], 0, 0, 0);
    }

    // epilogue: d~ = fl(fl(a+b) - acc*2^-12); key = ((d~-a)*2^16 + 32768)<<13 | k (exact ints)
    unsigned* tk = (kt < 32) ? tk0 : tk1;
    const int gloc0 = (kt & 31) * 8 + wcol * 4;
    float bvv[4];
    #pragma unroll
    for (int j = 0; j < 4; ++j) bvv[j] = bsq[k0 + wcol * 64 + j * 16 + lm];
    #pragma unroll
    for (int i = 0; i < 4; ++i) {
        #pragma unroll
        for (int r = 0; r < 4; ++r) {
            int m = n0 + wrow * 64 + i * 16 + quad * 4 + r;
            float a = asq[m];
            #pragma unroll
            for (int j = 0; j < 4; ++j) {
                float dd = (a + bvv[j]) - acc[i][j][r] * 2.44140625e-4f;  // 2*(acc*2^-13), exact
                float gv = dd - a;                                        // Sterbenz: exact, mult of 2^-16
                int mi = (int)(gv * 65536.0f) + 32768;
                unsigned key = ((unsigned)mi << 13) | (unsigned)(k0 + wcol * 64 + j * 16 + lm);
                #pragma unroll
                for (int xm = 1; xm < 16; xm <<= 1) {
                    unsigned o = __shfl_xor(key, xm, 64);
                    key = o < key ? o : key;
                }
                if (lm == 0) tk[(size_t)m * 256 + gloc0 + j] = key;
            }
        }
    }
}

// ---- reduce 512 group-keys per n -> global min, build worklist, init final ----
__global__ __launch_bounds__(256) void k_red2(const unsigned* __restrict__ tk0,
        const unsigned* __restrict__ tk1, unsigned long long* __restrict__ fin,
        unsigned* __restrict__ wl, int* __restrict__ wcnt) {
    int n = blockIdx.x * 4 + (threadIdx.x >> 6);
    int lane = threadIdx.x & 63;
    unsigned keys[8];
    unsigned mn = 0xFFFFFFFFu;
    #pragma unroll
    for (int jj = 0; jj < 8; ++jj) {
        const unsigned* base = (jj < 4) ? tk0 : tk1;
        int gl = lane + 64 * jj;
        keys[jj] = base[(size_t)n * 256 + (gl & 255)];
        mn = keys[jj] < mn ? keys[jj] : mn;
    }
    #pragma unroll
    for (int m = 1; m < 64; m <<= 1) {
        unsigned o = __shfl_xor(mn, m, 64);
        mn = o < mn ? o : mn;
    }
    unsigned thresh = (mn >> 13) + 8;   // eps = 8 * 2^-16 = 1.22e-4 >= 2*delta
    #pragma unroll
    for (int jj = 0; jj < 8; ++jj) {
        if ((keys[jj] >> 13) <= thresh) {
            int pos = atomicAdd(wcnt, 1);
            if (pos < WLCAP) wl[pos] = ((unsigned)n << 9) | (unsigned)(lane + 64 * jj);
        }
    }
    if (lane == 0) fin[n] = ~0ull;
}

// ---- exact 3-product recompute for candidate (n, 16-k-group) items ----
__global__ __launch_bounds__(256) void k_exact(
        const _Float16* __restrict__ Ah, const _Float16* __restrict__ Am,
        const _Float16* __restrict__ Bh, const _Float16* __restrict__ Bm,
        const float* __restrict__ asq, const float* __restrict__ bsq,
        const unsigned* __restrict__ wl, const int* __restrict__ wcnt,
        unsigned long long* __restrict__ fin) {
    int wid = blockIdx.x * 4 + (threadIdx.x >> 6);
    int lane = threadIdx.x & 63;
    int lm = lane & 15, quad = lane >> 4;
    int count = *wcnt; if (count > WLCAP) count = WLCAP;
    int nw = gridDim.x * 4;
    for (int it = wid; it < count; it += nw) {
        unsigned item = wl[it];
        int n = item >> 9, g = item & 511;
        int n0 = n & ~15;
        const _Float16* ap  = Ah + (size_t)(n0 + lm) * 256 + quad * 8;
        const _Float16* amp = Am + (size_t)(n0 + lm) * 256 + quad * 8;
        const _Float16* bp  = Bh + (size_t)(g * 16 + lm) * 256 + quad * 8;
        const _Float16* bmp = Bm + (size_t)(g * 16 + lm) * 256 + quad * 8;
        v4f a1 = (v4f){0.f, 0.f, 0.f, 0.f}, a2 = (v4f){0.f, 0.f, 0.f, 0.f};
        #pragma unroll
        for (int cb = 0; cb < 8; ++cb) {   // EXACT round-3 sequence: hh -> h*bm -> am*h
            v8h fa  = *(const v8h*)(ap  + cb * 32);
            v8h fam = *(const v8h*)(amp + cb * 32);
            v8h fb  = *(const v8h*)(bp  + cb * 32);
            v8h fbm = *(const v8h*)(bmp + cb * 32);
            a1 = __builtin_amdgcn_mfma_f32_16x16x32_f16(fa,  fb,  a1, 0, 0, 0);
            a2 = __builtin_amdgcn_mfma_f32_16x16x32_f16(fa,  fbm, a2, 0, 0, 0);
            a2 = __builtin_amdgcn_mfma_f32_16x16x32_f16(fam, fb,  a2, 0, 0, 0);
        }
        int reg_n = n & 3, quad_n = (n >> 2) & 3;   // wave-uniform
        float A1 = a1[reg_n], A2 = a2[reg_n];
        float S = fmaf(A2, 4.8828125e-4f, A1) * 1.220703125e-4f;
        int k = g * 16 + lm;
        float dd = (asq[n] + bsq[k]) - 2.0f * S;
        unsigned long long key = ((unsigned long long)__float_as_uint(dd) << 13) | (unsigned)k;
        unsigned long long kk = (quad == quad_n) ? key : ~0ull;
        #pragma unroll
        for (int m = 1; m < 64; m <<= 1) {
            unsigned long long o = __shfl_xor(kk, m, 64);
            kk = o < kk ? o : kk;
        }
        if (lane == 0) atomicMin(fin + n, kk);
    }
}

// ---- z_q gather + ST write + loss + dw scatter + idx finalize + histogram ----
__global__ __launch_bounds__(256) void k_zq(const float* __restrict__ z, const float* __restrict__ emb,
        const unsigned long long* __restrict__ fin, float* __restrict__ out_zq,
        float* __restrict__ dw, float* __restrict__ scal,
        float* __restrict__ out_idx, int* __restrict__ cnt) {
    int n0 = blockIdx.x * 64, c00 = blockIdx.y * 64;
    int lane = threadIdx.x & 63, g = threadIdx.x >> 6;
    int n = n0 + lane;
    int b = n >> 10, hw = n & 1023;
    int idxn = (int)(fin[n] & 8191ull);
    if (blockIdx.y == 0 && g == 0) {
        out_idx[n] = (float)idxn;
        atomicAdd(cnt + idxn, 1);
    }
    const float* zr = z + (size_t)b * CHW + hw;
    const float* er = emb + (size_t)idxn * 256;
    float* dwr = dw + (size_t)idxn * 256;
    float* oz = out_zq + (size_t)b * CHW + hw;
    float ls = 0.f;
    #pragma unroll
    for (int q = 0; q < 4; ++q) {
        int c = c00 + g * 16 + q * 4;
        float4 e4 = *(const float4*)(er + c);
        float ev[4] = {e4.x, e4.y, e4.z, e4.w};
        #pragma unroll
        for (int r = 0; r < 4; ++r) {
            float zp = zr[(size_t)(c + r) << 10];
            float dif = ev[r] - zp;
            oz[(size_t)(c + r) << 10] = zp + dif;
            ls = fmaf(dif, dif, ls);
            atomicAdd(dwr + c + r, zp);
        }
    }
    #pragma unroll
    for (int m = 1; m < 64; m <<= 1) ls += __shfl_xor(ls, m, 64);
    __shared__ float red[4];
    if (lane == 0) red[g] = ls;
    __syncthreads();
    if (threadIdx.x == 0) atomicAdd(scal, red[0] + red[1] + red[2] + red[3]);
}

// ---- finalize: new_cs (folded), new_ema_w, new_embedding, loss ----
__global__ __launch_bounds__(256) void k_fin(const float* __restrict__ cs, const float* __restrict__ ema,
        const float* __restrict__ dw, const float* __restrict__ scal, const int* __restrict__ cnt,
        float* __restrict__ out_ncs, float* __restrict__ out_ema,
        float* __restrict__ out_emb, float* __restrict__ out_loss) {
    int k = blockIdx.x * 4 + (threadIdx.x >> 6);
    int lane = threadIdx.x & 63;
    const float C1 = (float)(1.0 - 0.99);
    const float KEPS = (float)(8192 * 1e-5);
    float ncs0v = cs[k] * 0.99f + C1 * (float)cnt[k];
    float nsum = 0.99f * scal[1] + C1 * 8192.0f;   // sum(counts) == N == 8192 always
    float ncs = (ncs0v + 1e-5f) / (nsum + KEPS) * nsum;
    if (lane == 0) out_ncs[k] = ncs;
    size_t base = (size_t)k * 256 + lane * 4;
    float4 e4 = *(const float4*)(ema + base);
    float4 d4 = *(const float4*)(dw + base);
    float r0 = e4.x * 0.99f + C1 * d4.x;
    float r1 = e4.y * 0.99f + C1 * d4.y;
    float r2 = e4.z * 0.99f + C1 * d4.z;
    float r3 = e4.w * 0.99f + C1 * d4.w;
    out_ema[base + 0] = r0; out_ema[base + 1] = r1; out_ema[base + 2] = r2; out_ema[base + 3] = r3;
    out_emb[base + 0] = r0 / ncs; out_emb[base + 1] = r1 / ncs;
    out_emb[base + 2] = r2 / ncs; out_emb[base + 3] = r3 / ncs;
    if (blockIdx.x == 0 && threadIdx.x == 0) {
        float m = scal[0] * (1.0f / 2097152.0f);
        out_loss[0] = m + 0.25f * m;
    }
}

extern "C" void kernel_launch(void* const* d_in, const int* in_sizes, int n_in,
                              void* d_out, int out_size, void* d_ws, size_t ws_size,
                              hipStream_t stream) {
    const float* z   = (const float*)d_in[0];
    const float* emb = (const float*)d_in[1];
    const float* cs  = (const float*)d_in[2];
    const float* ema = (const float*)d_in[3];
    float* out = (float*)d_out;
    float* wsf = (float*)d_ws;

    float* asq  = wsf + OFF_ASQ;
    float* bsq  = wsf + OFF_BSQ;
    int*   cnt  = (int*)(wsf + OFF_CNT);
    float* scal = wsf + OFF_SCAL;
    int*   wcnt = (int*)(wsf + OFF_WCNT);
    float* dw   = wsf + OFF_DW;
    unsigned long long* fin = (unsigned long long*)(wsf + OFF_FIN);
    unsigned* wl = (unsigned*)(wsf + OFF_WL);
    _Float16* Bh = (_Float16*)(wsf + OFF_BH);
    _Float16* Bm = (_Float16*)(wsf + OFF_BM);

    float* out_zq   = out;                 // [2097152]
    float* out_loss = out + 2097152;       // [1]
    float* out_idx  = out + 2097153;       // [8192]
    float* out_ncs  = out + 2105345;       // [8192]
    float* out_ema  = out + 2113537;       // [2097152]
    float* out_emb  = out + 4210689;       // [2097152]

    // scratch aliased into dead d_out regions (all dead until k_zq / k_fin):
    unsigned* tk0 = (unsigned*)out;                      // groups 0..255   (out_zq, 8 MB)
    unsigned* tk1 = (unsigned*)(out + 4210689);          // groups 256..511 (out_emb, 8 MB)
    _Float16* Ah = (_Float16*)(out + 2097156);           // 4 MB, 16B-aligned (idx/ncs/ema window)
    _Float16* Am = (_Float16*)(out + 2097156 + 1048576); // 4 MB, ends before out_emb

    // zero cnt + scal + wcnt + dw (contiguous)
    hipMemsetAsync(wsf + OFF_CNT, 0, (size_t)(OFF_DW + 2097152 - OFF_CNT) * sizeof(float), stream);

    k_prep0<<<2080, 256, 0, stream>>>(z, cs, emb, asq, bsq, Bh, Bm, scal);
    prep_z<<<512, 256, 0, stream>>>(z, Ah, Am);
    k_pass1<<<dim3(64, 64), 256, 0, stream>>>(Ah, Bh, asq, bsq, tk0, tk1);
    k_red2<<<2048, 256, 0, stream>>>(tk0, tk1, fin, wl, wcnt);
    k_exact<<<512, 256, 0, stream>>>(Ah, Am, Bh, Bm, asq, bsq, wl, wcnt, fin);
    k_zq<<<dim3(128, 4), 256, 0, stream>>>(z, emb, fin, out_zq, dw, scal, out_idx, cnt);
    k_fin<<<2048, 256, 0, stream>>>(cs, ema, dw, scal, cnt, out_ncs, out_ema, out_emb, out_loss);
}

// Round 5
// 260.721 us; speedup vs baseline: 1.9084x; 1.9084x over previous
//
#include <hip/hip_runtime.h>

#define CHW 262144   // C*H*W = 256*32*32
#define HWD 1024     // H*W

typedef _Float16 v8h __attribute__((ext_vector_type(8)));
typedef _Float16 v4h __attribute__((ext_vector_type(4)));
typedef float    v4f __attribute__((ext_vector_type(4)));

// ws layout (float offsets), total 5275656 floats = 21.10 MB (<= 21.13 proven r1)
static const unsigned OFF_ASQ  = 0;        // ||z_n||^2 [8192]
static const unsigned OFF_BSQ  = 8192;     // ||e_k||^2 [8192]
static const unsigned OFF_CNT  = 16384;    // counts (int, ZEROED) [8192]
static const unsigned OFF_HEAD = 24576;    // per-code list head, n+1, 0=end (int, ZEROED) [8192]
static const unsigned OFF_SCAL = 32768;    // [0]=loss_sum [1]=sum(cs) (ZEROED) [8]
static const unsigned OFF_DW   = 32776;    // dw [2097152] (written fully by k_dw, no zero needed)
static const unsigned OFF_PDK  = 2129928;  // u32 keys [8192][128] (1048576 floats)
static const unsigned OFF_BH   = 3178504;  // Bh fp16 [8192*256] (1048576 floats)
static const unsigned OFF_BM   = 4227080;  // Bm fp16

#define GLL(g, l) __builtin_amdgcn_global_load_lds( \
    (const __attribute__((address_space(1))) void*)(g), \
    (__attribute__((address_space(3))) void*)(l), 16, 0, 0)

// ---- stage 1: ||z||^2 + sum(cs) | emb->bsq+fp16 split | z transpose+split+zf32 ----
__global__ __launch_bounds__(256) void k_prep(const float* __restrict__ z, const float* __restrict__ cs,
        const float* __restrict__ emb, float* __restrict__ asq, float* __restrict__ bsq,
        _Float16* __restrict__ Bh, _Float16* __restrict__ Bm,
        _Float16* __restrict__ Ah, _Float16* __restrict__ Am,
        float* __restrict__ zf32, float* __restrict__ scal) {
    int bx = blockIdx.x;
    int t = threadIdx.x;
    if (bx < 32) {
        // ||z_n||^2 — EXACT sequential 256-chain (bits feed the argmin; do not reorder)
        int n = bx * 256 + t;
        const float* p = z + (size_t)(n >> 10) * CHW + (n & 1023);
        float s = 0.f;
        #pragma unroll 8
        for (int c = 0; c < 256; ++c) { float v = p[(size_t)c << 10]; s = fmaf(v, v, s); }
        asq[n] = s;
        // sum(cluster_size) — loose tolerance
        float cv = cs[n];
        #pragma unroll
        for (int m = 1; m < 64; m <<= 1) cv += __shfl_xor(cv, m, 64);
        if ((t & 63) == 0) atomicAdd(scal + 1, cv);
    } else if (bx < 2080) {
        int w = (bx - 32) * 4 + (t >> 6);
        int lane = t & 63;
        float4 v = *(const float4*)(emb + (size_t)w * 256 + lane * 4);
        float s = v.x * v.x;
        s = fmaf(v.y, v.y, s); s = fmaf(v.z, v.z, s); s = fmaf(v.w, v.w, s);
        #pragma unroll
        for (int m = 1; m < 64; m <<= 1) s += __shfl_xor(s, m, 64);
        if (lane == 0) bsq[w] = s;
        float e0 = v.x * 8192.0f, e1 = v.y * 8192.0f, e2 = v.z * 8192.0f, e3 = v.w * 8192.0f;
        _Float16 h0 = (_Float16)e0, h1 = (_Float16)e1, h2 = (_Float16)e2, h3 = (_Float16)e3;
        v4h hv = {h0, h1, h2, h3};
        v4h mv = {(_Float16)((e0 - (float)h0) * 2048.0f),
                  (_Float16)((e1 - (float)h1) * 2048.0f),
                  (_Float16)((e2 - (float)h2) * 2048.0f),
                  (_Float16)((e3 - (float)h3) * 2048.0f)};
        *(v4h*)(Bh + (size_t)w * 256 + lane * 4) = hv;
        *(v4h*)(Bm + (size_t)w * 256 + lane * 4) = mv;
    } else {
        __shared__ float s[64][65];
        int blk = bx - 2080;
        int hw0 = (blk & 15) * 64;
        int c0  = ((blk >> 4) & 3) * 64;
        int b   = blk >> 6;
        #pragma unroll
        for (int ii = 0; ii < 16; ++ii) {
            int e = t + ii * 256;
            int c = e >> 6, x = e & 63;
            s[c][x] = z[(size_t)b * CHW + (size_t)(c0 + c) * HWD + hw0 + x];
        }
        __syncthreads();
        int n = t & 63, cseg = (t >> 6) * 16;
        _Float16 hbuf[16], mbuf[16];
        float fbuf[16];
        #pragma unroll
        for (int j = 0; j < 16; ++j) {
            float v = s[cseg + j][n];
            _Float16 h = (_Float16)v;
            float r = v - (float)h;
            fbuf[j] = v;
            hbuf[j] = h;
            mbuf[j] = (_Float16)(r * 2048.0f);
        }
        size_t off = ((size_t)b * 1024 + hw0 + n) * 256 + c0 + cseg;
        *(v8h*)(Ah + off)     = *(v8h*)(hbuf);
        *(v8h*)(Ah + off + 8) = *(v8h*)(hbuf + 8);
        *(v8h*)(Am + off)     = *(v8h*)(mbuf);
        *(v8h*)(Am + off + 8) = *(v8h*)(mbuf + 8);
        #pragma unroll
        for (int q = 0; q < 4; ++q)
            *(float4*)(zf32 + off + q * 4) = *(float4*)(fbuf + q * 4);
    }
}

// ---- main: 128x128 MFMA tiles, dbuf LDS, 3-product fp16x2, u32 key epilogue ----
__global__ __launch_bounds__(256, 2) void k_main(
        const _Float16* __restrict__ Ah, const _Float16* __restrict__ Am,
        const _Float16* __restrict__ Bh, const _Float16* __restrict__ Bm,
        const float* __restrict__ asq, const float* __restrict__ bsq,
        unsigned* __restrict__ pdk) {
    __shared__ _Float16 lds[32768];  // 64 KB: 2 buf x (4 mats x [128 rows x 32 halves]), XOR-swizzled
    const int kt = blockIdx.x, nt = blockIdx.y;
    const int n0 = nt * 128, k0 = kt * 128;
    const int t = threadIdx.x;
    const int lane = t & 63, w = t >> 6;
    const int wrow = w >> 1, wcol = w & 1;
    const int lm = lane & 15, quad = lane >> 4;

    v4f acc1[4][4], acc2[4][4];
    #pragma unroll
    for (int i = 0; i < 4; ++i)
        #pragma unroll
        for (int j = 0; j < 4; ++j) { acc1[i][j] = (v4f){0.f,0.f,0.f,0.f}; acc2[i][j] = (v4f){0.f,0.f,0.f,0.f}; }

    const int row0 = t >> 2;
    const int c40 = (t & 3) ^ ((row0 >> 1) & 3);
    const char* gA0  = (const char*)Ah + (size_t)(n0 + row0) * 512 + c40 * 16;
    const char* gAm0 = (const char*)Am + (size_t)(n0 + row0) * 512 + c40 * 16;
    const char* gB0  = (const char*)Bh + (size_t)(k0 + row0) * 512 + c40 * 16;
    const char* gBm0 = (const char*)Bm + (size_t)(k0 + row0) * 512 + c40 * 16;

    int sa[4], sb[4];
    #pragma unroll
    for (int i = 0; i < 4; ++i) {
        int mr = wrow * 64 + i * 16 + lm;
        sa[i] = mr * 32 + ((quad ^ ((mr >> 1) & 3)) * 8);
        int nr = wcol * 64 + i * 16 + lm;
        sb[i] = nr * 32 + ((quad ^ ((nr >> 1) & 3)) * 8);
    }

    auto stage = [&](int cb, int buf) {
        const size_t co = (size_t)cb * 64;
        _Float16* l0 = lds + buf * 16384 + t * 8;
        _Float16* l1 = l0 + 2048;
        GLL(gA0 + co,           l0);
        GLL(gA0 + co + 32768,   l1);
        GLL(gAm0 + co,          l0 + 4096);
        GLL(gAm0 + co + 32768,  l1 + 4096);
        GLL(gB0 + co,           l0 + 8192);
        GLL(gB0 + co + 32768,   l1 + 8192);
        GLL(gBm0 + co,          l0 + 12288);
        GLL(gBm0 + co + 32768,  l1 + 12288);
    };

    stage(0, 0);
    for (int cb = 0; cb < 8; ++cb) {
        __syncthreads();
        if (cb < 7) stage(cb + 1, (cb + 1) & 1);
        const _Float16* L = lds + (cb & 1) * 16384;

        v8h fa[4], fam[4], fb[4], fbm[4];
        #pragma unroll
        for (int i = 0; i < 4; ++i) {
            fa[i]  = *(const v8h*)(L + sa[i]);
            fam[i] = *(const v8h*)(L + 4096 + sa[i]);
            fb[i]  = *(const v8h*)(L + 8192 + sb[i]);
            fbm[i] = *(const v8h*)(L + 12288 + sb[i]);
        }
        #pragma unroll
        for (int i = 0; i < 4; ++i)
            #pragma unroll
            for (int j = 0; j < 4; ++j) {
                acc1[i][j] = __builtin_amdgcn_mfma_f32_16x16x32_f16(fa[i], fb[j], acc1[i][j], 0, 0, 0);
                acc2[i][j] = __builtin_amdgcn_mfma_f32_16x16x32_f16(fa[i], fbm[j], acc2[i][j], 0, 0, 0);
                acc2[i][j] = __builtin_amdgcn_mfma_f32_16x16x32_f16(fam[i], fb[j], acc2[i][j], 0, 0, 0);
            }
    }

    // epilogue: d = fl(fl(a+b) - 2*S); u32 key = ((d - a)*2^16 + 32768)<<13 | k
    // (d - a) is Sterbenz-exact and a multiple of 2^-16 -> key order == (d, k) order.
    float bvv[4];
    #pragma unroll
    for (int j = 0; j < 4; ++j) bvv[j] = bsq[k0 + wcol * 64 + j * 16 + lm];
    #pragma unroll
    for (int i = 0; i < 4; ++i) {
        #pragma unroll
        for (int r = 0; r < 4; ++r) {
            int m = n0 + wrow * 64 + i * 16 + quad * 4 + r;
            float av_ = asq[m];
            unsigned best = 0xFFFFFFFFu;
            #pragma unroll
            for (int j = 0; j < 4; ++j) {
                float S = fmaf(acc2[i][j][r], 4.8828125e-4f, acc1[i][j][r]) * 1.220703125e-4f;
                float dd = (av_ + bvv[j]) - 2.0f * S;      // SAME BITS as round 3
                float gv = dd - av_;                        // exact (Sterbenz)
                int mi = (int)(gv * 65536.0f) + 32768;      // exact integer
                int col = k0 + wcol * 64 + j * 16 + lm;
                unsigned key = ((unsigned)mi << 13) | (unsigned)col;
                best = key < best ? key : best;
            }
            #pragma unroll
            for (int xm = 1; xm < 16; xm <<= 1) {
                unsigned o = __shfl_xor(best, xm, 64);
                best = o < best ? o : best;
            }
            if (lm == 0) pdk[(size_t)m * 128 + kt * 2 + wcol] = best;
        }
    }
}

// ---- reduce 128 keys/n -> idx, histogram, per-code linked lists ----
__global__ __launch_bounds__(256) void k_red(const unsigned* __restrict__ pdk,
        float* __restrict__ out_idx, int* __restrict__ cnt,
        int* __restrict__ head, int* __restrict__ nxt) {
    int n = blockIdx.x * 4 + (threadIdx.x >> 6);
    int lane = threadIdx.x & 63;
    unsigned a = pdk[(size_t)n * 128 + lane];
    unsigned b = pdk[(size_t)n * 128 + 64 + lane];
    unsigned v = a < b ? a : b;
    #pragma unroll
    for (int m = 1; m < 64; m <<= 1) {
        unsigned o = __shfl_xor(v, m, 64);
        v = o < v ? o : v;
    }
    if (lane == 0) {
        int k = (int)(v & 8191u);
        out_idx[n] = (float)k;
        atomicAdd(cnt + k, 1);
        int old = atomicExch(head + k, n + 1);   // 0 = end-of-list
        nxt[n] = old;
    }
}

// ---- dw[k] = sum of zf rows assigned to k (list walk, no atomics) ----
__global__ __launch_bounds__(256) void k_dw(const int* __restrict__ head, const int* __restrict__ nxt,
        const float* __restrict__ zf32, float* __restrict__ dw) {
    int kk = blockIdx.x * 4 + (threadIdx.x >> 6);
    int lane = threadIdx.x & 63;
    float4 acc = {0.f, 0.f, 0.f, 0.f};
    int cur = head[kk];                 // wave-uniform walk
    while (cur) {
        int n = cur - 1;
        float4 v = *(const float4*)(zf32 + (size_t)n * 256 + lane * 4);
        acc.x += v.x; acc.y += v.y; acc.z += v.z; acc.w += v.w;
        cur = nxt[n];
    }
    *(float4*)(dw + (size_t)kk * 256 + lane * 4) = acc;
}

// ---- z_q gather + straight-through write + loss (no dw atomics) ----
__global__ __launch_bounds__(256) void k_zq(const float* __restrict__ z, const float* __restrict__ emb,
        const float* __restrict__ out_idx, float* __restrict__ out_zq, float* __restrict__ scal) {
    int n0 = blockIdx.x * 64, c00 = blockIdx.y * 64;
    int lane = threadIdx.x & 63, g = threadIdx.x >> 6;
    int n = n0 + lane;
    int b = n >> 10, hw = n & 1023;
    int idxn = (int)out_idx[n];
    const float* zr = z + (size_t)b * CHW + hw;
    const float* er = emb + (size_t)idxn * 256;
    float* oz = out_zq + (size_t)b * CHW + hw;
    float ls = 0.f;
    #pragma unroll
    for (int q = 0; q < 4; ++q) {
        int c = c00 + g * 16 + q * 4;
        float4 e4 = *(const float4*)(er + c);
        float ev[4] = {e4.x, e4.y, e4.z, e4.w};
        #pragma unroll
        for (int r = 0; r < 4; ++r) {
            float zp = zr[(size_t)(c + r) << 10];
            float dif = ev[r] - zp;
            oz[(size_t)(c + r) << 10] = zp + dif;
            ls = fmaf(dif, dif, ls);
        }
    }
    #pragma unroll
    for (int m = 1; m < 64; m <<= 1) ls += __shfl_xor(ls, m, 64);
    __shared__ float red[4];
    if (lane == 0) red[g] = ls;
    __syncthreads();
    if (threadIdx.x == 0) atomicAdd(scal, red[0] + red[1] + red[2] + red[3]);
}

// ---- finalize: new_cs (folded), new_ema_w, new_embedding, loss ----
__global__ __launch_bounds__(256) void k_fin(const float* __restrict__ cs, const float* __restrict__ ema,
        const float* __restrict__ dw, const float* __restrict__ scal, const int* __restrict__ cnt,
        float* __restrict__ out_ncs, float* __restrict__ out_ema,
        float* __restrict__ out_emb, float* __restrict__ out_loss) {
    int k = blockIdx.x * 4 + (threadIdx.x >> 6);
    int lane = threadIdx.x & 63;
    const float C1 = (float)(1.0 - 0.99);
    const float KEPS = (float)(8192 * 1e-5);
    float ncs0v = cs[k] * 0.99f + C1 * (float)cnt[k];
    float nsum = 0.99f * scal[1] + C1 * 8192.0f;   // sum(counts) == N == 8192
    float ncs = (ncs0v + 1e-5f) / (nsum + KEPS) * nsum;
    if (lane == 0) out_ncs[k] = ncs;
    size_t base = (size_t)k * 256 + lane * 4;
    float4 e4 = *(const float4*)(ema + base);
    float4 d4 = *(const float4*)(dw + base);
    float r0 = e4.x * 0.99f + C1 * d4.x;
    float r1 = e4.y * 0.99f + C1 * d4.y;
    float r2 = e4.z * 0.99f + C1 * d4.z;
    float r3 = e4.w * 0.99f + C1 * d4.w;
    out_ema[base + 0] = r0; out_ema[base + 1] = r1; out_ema[base + 2] = r2; out_ema[base + 3] = r3;
    out_emb[base + 0] = r0 / ncs; out_emb[base + 1] = r1 / ncs;
    out_emb[base + 2] = r2 / ncs; out_emb[base + 3] = r3 / ncs;
    if (blockIdx.x == 0 && threadIdx.x == 0) {
        float m = scal[0] * (1.0f / 2097152.0f);
        out_loss[0] = m + 0.25f * m;
    }
}

extern "C" void kernel_launch(void* const* d_in, const int* in_sizes, int n_in,
                              void* d_out, int out_size, void* d_ws, size_t ws_size,
                              hipStream_t stream) {
    const float* z   = (const float*)d_in[0];
    const float* emb = (const float*)d_in[1];
    const float* cs  = (const float*)d_in[2];
    const float* ema = (const float*)d_in[3];
    float* out = (float*)d_out;
    float* wsf = (float*)d_ws;

    float* asq  = wsf + OFF_ASQ;
    float* bsq  = wsf + OFF_BSQ;
    int*   cnt  = (int*)(wsf + OFF_CNT);
    int*   head = (int*)(wsf + OFF_HEAD);
    float* scal = wsf + OFF_SCAL;
    float* dw   = wsf + OFF_DW;
    unsigned* pdk = (unsigned*)(wsf + OFF_PDK);
    _Float16* Bh = (_Float16*)(wsf + OFF_BH);
    _Float16* Bm = (_Float16*)(wsf + OFF_BM);

    float* out_zq   = out;                 // [2097152]
    float* out_loss = out + 2097152;       // [1]
    float* out_idx  = out + 2097153;       // [8192]
    float* out_ncs  = out + 2105345;       // [8192]
    float* out_ema  = out + 2113537;       // [2097152]
    float* out_emb  = out + 4210689;       // [2097152]

    // scratch aliased into dead d_out regions:
    float* zf32 = out;                                   // out_zq region, dead until k_zq
    _Float16* Ah = (_Float16*)(out + 2097156);           // ema-region window, dead until k_fin
    _Float16* Am = (_Float16*)(out + 2097156 + 1048576);
    int* nxt = (int*)(out + 2105345);                    // out_ncs region, dead until k_fin

    // zero cnt + head + scal (contiguous, 64 KB)
    hipMemsetAsync(wsf + OFF_CNT, 0, (size_t)(OFF_SCAL + 8 - OFF_CNT) * sizeof(float), stream);

    k_prep<<<2592, 256, 0, stream>>>(z, cs, emb, asq, bsq, Bh, Bm, Ah, Am, zf32, scal);
    k_main<<<dim3(64, 64), 256, 0, stream>>>(Ah, Am, Bh, Bm, asq, bsq, pdk);
    k_red<<<2048, 256, 0, stream>>>(pdk, out_idx, cnt, head, nxt);
    k_dw<<<2048, 256, 0, stream>>>(head, nxt, zf32, dw);
    k_zq<<<dim3(128, 4), 256, 0, stream>>>(z, emb, out_idx, out_zq, scal);
    k_fin<<<2048, 256, 0, stream>>>(cs, ema, dw, scal, cnt, out_ncs, out_ema, out_emb, out_loss);
}

// Round 6
// 247.392 us; speedup vs baseline: 2.0112x; 1.0539x over previous
//
#include <hip/hip_runtime.h>

#define CHW 262144   // C*H*W = 256*32*32
#define HWD 1024     // H*W

typedef _Float16 v8h __attribute__((ext_vector_type(8)));
typedef _Float16 v4h __attribute__((ext_vector_type(4)));
typedef float    v4f __attribute__((ext_vector_type(4)));

// ws layout (float offsets), total 3186696 floats = 12.75 MB (ws >= 21.1 MB proven r1)
static const unsigned OFF_ASQ  = 0;        // ||z_n||^2 [8192]
static const unsigned OFF_BSQ  = 8192;     // ||e_k||^2 [8192]
static const unsigned OFF_CNT  = 16384;    // counts (int, zeroed by k_prep) [8192]
static const unsigned OFF_HEAD = 24576;    // list heads, n+1, 0=end (int, zeroed) [8192]
static const unsigned OFF_SCAL = 32768;    // [0]=loss_sum [1]=sum(cs) (zeroed) [8]
static const unsigned OFF_NXT  = 32776;    // list next (int) [8192]
static const unsigned OFF_ZF   = 40968;    // zf32 [n][c] [2097152]
static const unsigned OFF_BH   = 2138120;  // Bh fp16 [8192*256] (1048576 floats, 16B-aligned)

#define GLL(g, l) __builtin_amdgcn_global_load_lds( \
    (const __attribute__((address_space(1))) void*)(g), \
    (__attribute__((address_space(3))) void*)(l), 16, 0, 0)

// ---- stage 1: ||z||^2 | emb->bsq+fp16 split | z transpose+split+zf32 | zero cnt/head/scal ----
__global__ __launch_bounds__(256) void k_prep(const float* __restrict__ z,
        const float* __restrict__ emb, float* __restrict__ asq, float* __restrict__ bsq,
        _Float16* __restrict__ Bh, _Float16* __restrict__ Bm,
        _Float16* __restrict__ Ah, _Float16* __restrict__ Am,
        float* __restrict__ zf32, float* __restrict__ zerobase) {
    int bx = blockIdx.x;
    int t = threadIdx.x;
    if (bx < 32) {
        // ||z_n||^2 — EXACT sequential 256-chain (bits feed the argmin; do not reorder)
        int n = bx * 256 + t;
        const float* p = z + (size_t)(n >> 10) * CHW + (n & 1023);
        float s = 0.f;
        #pragma unroll 8
        for (int c = 0; c < 256; ++c) { float v = p[(size_t)c << 10]; s = fmaf(v, v, s); }
        asq[n] = s;
    } else if (bx < 2080) {
        int w = (bx - 32) * 4 + (t >> 6);
        int lane = t & 63;
        float4 v = *(const float4*)(emb + (size_t)w * 256 + lane * 4);
        float s = v.x * v.x;
        s = fmaf(v.y, v.y, s); s = fmaf(v.z, v.z, s); s = fmaf(v.w, v.w, s);
        #pragma unroll
        for (int m = 1; m < 64; m <<= 1) s += __shfl_xor(s, m, 64);
        if (lane == 0) bsq[w] = s;
        float e0 = v.x * 8192.0f, e1 = v.y * 8192.0f, e2 = v.z * 8192.0f, e3 = v.w * 8192.0f;
        _Float16 h0 = (_Float16)e0, h1 = (_Float16)e1, h2 = (_Float16)e2, h3 = (_Float16)e3;
        v4h hv = {h0, h1, h2, h3};
        v4h mv = {(_Float16)((e0 - (float)h0) * 2048.0f),
                  (_Float16)((e1 - (float)h1) * 2048.0f),
                  (_Float16)((e2 - (float)h2) * 2048.0f),
                  (_Float16)((e3 - (float)h3) * 2048.0f)};
        *(v4h*)(Bh + (size_t)w * 256 + lane * 4) = hv;
        *(v4h*)(Bm + (size_t)w * 256 + lane * 4) = mv;
    } else if (bx < 2592) {
        __shared__ float s[64][65];
        int blk = bx - 2080;
        int hw0 = (blk & 15) * 64;
        int c0  = ((blk >> 4) & 3) * 64;
        int b   = blk >> 6;
        #pragma unroll
        for (int ii = 0; ii < 16; ++ii) {
            int e = t + ii * 256;
            int c = e >> 6, x = e & 63;
            s[c][x] = z[(size_t)b * CHW + (size_t)(c0 + c) * HWD + hw0 + x];
        }
        __syncthreads();
        int n = t & 63, cseg = (t >> 6) * 16;
        _Float16 hbuf[16], mbuf[16];
        float fbuf[16];
        #pragma unroll
        for (int j = 0; j < 16; ++j) {
            float v = s[cseg + j][n];
            _Float16 h = (_Float16)v;
            float r = v - (float)h;
            fbuf[j] = v;
            hbuf[j] = h;
            mbuf[j] = (_Float16)(r * 2048.0f);
        }
        size_t off = ((size_t)b * 1024 + hw0 + n) * 256 + c0 + cseg;
        *(v8h*)(Ah + off)     = *(v8h*)(hbuf);
        *(v8h*)(Ah + off + 8) = *(v8h*)(hbuf + 8);
        *(v8h*)(Am + off)     = *(v8h*)(mbuf);
        *(v8h*)(Am + off + 8) = *(v8h*)(mbuf + 8);
        #pragma unroll
        for (int q = 0; q < 4; ++q)
            *(float4*)(zf32 + off + q * 4) = *(float4*)(fbuf + q * 4);
    } else {
        // zero cnt[8192] + head[8192] (+ scal[8])
        int idx = (bx - 2592) * 1024 + t * 4;
        *(float4*)(zerobase + idx) = (float4){0.f, 0.f, 0.f, 0.f};
        if (bx == 2607 && t == 0) {
            *(float4*)(zerobase + 16384) = (float4){0.f, 0.f, 0.f, 0.f};
            *(float4*)(zerobase + 16388) = (float4){0.f, 0.f, 0.f, 0.f};
        }
    }
}

// ---- main: 128x128 tile, 512 threads (8 waves of 32x64), dbuf LDS, 3-product fp16x2 ----
__global__ __launch_bounds__(512, 4) void k_main(
        const _Float16* __restrict__ Ah, const _Float16* __restrict__ Am,
        const _Float16* __restrict__ Bh, const _Float16* __restrict__ Bm,
        const float* __restrict__ asq, const float* __restrict__ bsq,
        unsigned* __restrict__ pdk) {
    __shared__ _Float16 lds[32768];  // 64 KB: 2 buf x (4 mats x [128 rows x 32 halves]), XOR-swizzled
    const int kt = blockIdx.x, nt = blockIdx.y;
    const int n0 = nt * 128, k0 = kt * 128;
    const int t = threadIdx.x;
    const int lane = t & 63, w = t >> 6;       // w in [0,8)
    const int wrow = w >> 1, wcol = w & 1;     // wave tile: rows wrow*32, cols wcol*64
    const int lm = lane & 15, quad = lane >> 4;

    v4f acc1[2][4], acc2[2][4];
    #pragma unroll
    for (int i = 0; i < 2; ++i)
        #pragma unroll
        for (int j = 0; j < 4; ++j) { acc1[i][j] = (v4f){0.f,0.f,0.f,0.f}; acc2[i][j] = (v4f){0.f,0.f,0.f,0.f}; }

    // staging: thread t -> chunk (row = t>>2, c4 = (t&3) ^ ((row>>1)&3)); one GLL per matrix
    const int row0 = t >> 2;                   // [0,128)
    const int c40 = (t & 3) ^ ((row0 >> 1) & 3);
    const char* gA  = (const char*)Ah + (size_t)(n0 + row0) * 512 + c40 * 16;
    const char* gAm = (const char*)Am + (size_t)(n0 + row0) * 512 + c40 * 16;
    const char* gB  = (const char*)Bh + (size_t)(k0 + row0) * 512 + c40 * 16;
    const char* gBm = (const char*)Bm + (size_t)(k0 + row0) * 512 + c40 * 16;

    int sa[2], sb[4];
    #pragma unroll
    for (int i = 0; i < 2; ++i) {
        int mr = wrow * 32 + i * 16 + lm;
        sa[i] = mr * 32 + ((quad ^ ((mr >> 1) & 3)) * 8);
    }
    #pragma unroll
    for (int j = 0; j < 4; ++j) {
        int nr = wcol * 64 + j * 16 + lm;
        sb[j] = nr * 32 + ((quad ^ ((nr >> 1) & 3)) * 8);
    }

    auto stage = [&](int cb, int buf) {
        const size_t co = (size_t)cb * 64;      // 32 halves per cb
        _Float16* l = lds + buf * 16384 + t * 8;  // lane-linear 16B dest per wave
        GLL(gA + co,  l);
        GLL(gAm + co, l + 4096);
        GLL(gB + co,  l + 8192);
        GLL(gBm + co, l + 12288);
    };

    stage(0, 0);
    for (int cb = 0; cb < 8; ++cb) {
        __syncthreads();
        if (cb < 7) stage(cb + 1, (cb + 1) & 1);
        const _Float16* L = lds + (cb & 1) * 16384;

        v8h fa[2], fam[2];
        #pragma unroll
        for (int i = 0; i < 2; ++i) {
            fa[i]  = *(const v8h*)(L + sa[i]);
            fam[i] = *(const v8h*)(L + 4096 + sa[i]);
        }
        #pragma unroll
        for (int jh = 0; jh < 2; ++jh) {       // j in halves to cap frag registers
            v8h fb0  = *(const v8h*)(L + 8192 + sb[jh * 2]);
            v8h fb1  = *(const v8h*)(L + 8192 + sb[jh * 2 + 1]);
            v8h fbm0 = *(const v8h*)(L + 12288 + sb[jh * 2]);
            v8h fbm1 = *(const v8h*)(L + 12288 + sb[jh * 2 + 1]);
            #pragma unroll
            for (int i = 0; i < 2; ++i) {
                int j0 = jh * 2;
                acc1[i][j0]     = __builtin_amdgcn_mfma_f32_16x16x32_f16(fa[i],  fb0,  acc1[i][j0], 0, 0, 0);
                acc2[i][j0]     = __builtin_amdgcn_mfma_f32_16x16x32_f16(fa[i],  fbm0, acc2[i][j0], 0, 0, 0);
                acc2[i][j0]     = __builtin_amdgcn_mfma_f32_16x16x32_f16(fam[i], fb0,  acc2[i][j0], 0, 0, 0);
                acc1[i][j0 + 1] = __builtin_amdgcn_mfma_f32_16x16x32_f16(fa[i],  fb1,  acc1[i][j0 + 1], 0, 0, 0);
                acc2[i][j0 + 1] = __builtin_amdgcn_mfma_f32_16x16x32_f16(fa[i],  fbm1, acc2[i][j0 + 1], 0, 0, 0);
                acc2[i][j0 + 1] = __builtin_amdgcn_mfma_f32_16x16x32_f16(fam[i], fb1,  acc2[i][j0 + 1], 0, 0, 0);
            }
        }
    }

    // epilogue: d = fl(fl(a+b) - 2*S); u32 key = ((d - a)*2^16 + 32768)<<13 | k  (exact ints)
    float bvv[4];
    #pragma unroll
    for (int j = 0; j < 4; ++j) bvv[j] = bsq[k0 + wcol * 64 + j * 16 + lm];
    #pragma unroll
    for (int i = 0; i < 2; ++i) {
        #pragma unroll
        for (int r = 0; r < 4; ++r) {
            int m = n0 + wrow * 32 + i * 16 + quad * 4 + r;
            float av_ = asq[m];
            unsigned best = 0xFFFFFFFFu;
            #pragma unroll
            for (int j = 0; j < 4; ++j) {
                float S = fmaf(acc2[i][j][r], 4.8828125e-4f, acc1[i][j][r]) * 1.220703125e-4f;
                float dd = (av_ + bvv[j]) - 2.0f * S;      // SAME BITS as rounds 3/5
                float gv = dd - av_;                        // exact (Sterbenz)
                int mi = (int)(gv * 65536.0f) + 32768;      // exact integer
                int col = k0 + wcol * 64 + j * 16 + lm;
                unsigned key = ((unsigned)mi << 13) | (unsigned)col;
                best = key < best ? key : best;
            }
            #pragma unroll
            for (int xm = 1; xm < 16; xm <<= 1) {           // reduce over lm within each quad
                unsigned o = __shfl_xor(best, xm, 64);
                best = o < best ? o : best;
            }
            if (lm == 0) pdk[(size_t)m * 128 + kt * 2 + wcol] = best;
        }
    }
}

// ---- reduce 128 keys/n -> idx, histogram, per-code linked lists; + sum(cs) ----
__global__ __launch_bounds__(256) void k_red(const unsigned* __restrict__ pdk,
        const float* __restrict__ cs, float* __restrict__ out_idx, int* __restrict__ cnt,
        int* __restrict__ head, int* __restrict__ nxt, float* __restrict__ scal) {
    int bx = blockIdx.x;
    int t = threadIdx.x;
    if (bx < 32) {
        float cv = cs[bx * 256 + t];
        #pragma unroll
        for (int m = 1; m < 64; m <<= 1) cv += __shfl_xor(cv, m, 64);
        if ((t & 63) == 0) atomicAdd(scal + 1, cv);
    }
    int n = bx * 4 + (t >> 6);
    int lane = t & 63;
    unsigned a = pdk[(size_t)n * 128 + lane];
    unsigned b = pdk[(size_t)n * 128 + 64 + lane];
    unsigned v = a < b ? a : b;
    #pragma unroll
    for (int m = 1; m < 64; m <<= 1) {
        unsigned o = __shfl_xor(v, m, 64);
        v = o < v ? o : v;
    }
    if (lane == 0) {
        int k = (int)(v & 8191u);
        out_idx[n] = (float)k;
        atomicAdd(cnt + k, 1);
        int old = atomicExch(head + k, n + 1);   // 0 = end-of-list
        nxt[n] = old;
    }
}

// ---- z_q gather + straight-through write + loss ----
__global__ __launch_bounds__(256) void k_zq(const float* __restrict__ z, const float* __restrict__ emb,
        const float* __restrict__ out_idx, float* __restrict__ out_zq, float* __restrict__ scal) {
    int n0 = blockIdx.x * 64, c00 = blockIdx.y * 64;
    int lane = threadIdx.x & 63, g = threadIdx.x >> 6;
    int n = n0 + lane;
    int b = n >> 10, hw = n & 1023;
    int idxn = (int)out_idx[n];
    const float* zr = z + (size_t)b * CHW + hw;
    const float* er = emb + (size_t)idxn * 256;
    float* oz = out_zq + (size_t)b * CHW + hw;
    float ls = 0.f;
    #pragma unroll
    for (int q = 0; q < 4; ++q) {
        int c = c00 + g * 16 + q * 4;
        float4 e4 = *(const float4*)(er + c);
        float ev[4] = {e4.x, e4.y, e4.z, e4.w};
        #pragma unroll
        for (int r = 0; r < 4; ++r) {
            float zp = zr[(size_t)(c + r) << 10];
            float dif = ev[r] - zp;
            oz[(size_t)(c + r) << 10] = zp + dif;
            ls = fmaf(dif, dif, ls);
        }
    }
    #pragma unroll
    for (int m = 1; m < 64; m <<= 1) ls += __shfl_xor(ls, m, 64);
    __shared__ float red[4];
    if (lane == 0) red[g] = ls;
    __syncthreads();
    if (threadIdx.x == 0) atomicAdd(scal, red[0] + red[1] + red[2] + red[3]);
}

// ---- finalize: list-walk dw (in regs), new_cs, new_ema_w, new_embedding, loss ----
__global__ __launch_bounds__(256) void k_fin(const float* __restrict__ cs, const float* __restrict__ ema,
        const int* __restrict__ head, const int* __restrict__ nxt, const float* __restrict__ zf32,
        const float* __restrict__ scal, const int* __restrict__ cnt,
        float* __restrict__ out_ncs, float* __restrict__ out_ema,
        float* __restrict__ out_emb, float* __restrict__ out_loss) {
    int k = blockIdx.x * 4 + (threadIdx.x >> 6);
    int lane = threadIdx.x & 63;
    // dw[k][:] = sum of zf rows assigned to k (wave-uniform list walk, no atomics)
    float4 dwv = {0.f, 0.f, 0.f, 0.f};
    int cur = head[k];
    while (cur) {
        int n = cur - 1;
        float4 v = *(const float4*)(zf32 + (size_t)n * 256 + lane * 4);
        dwv.x += v.x; dwv.y += v.y; dwv.z += v.z; dwv.w += v.w;
        cur = nxt[n];
    }
    const float C1 = (float)(1.0 - 0.99);
    const float KEPS = (float)(8192 * 1e-5);
    float ncs0v = cs[k] * 0.99f + C1 * (float)cnt[k];
    float nsum = 0.99f * scal[1] + C1 * 8192.0f;   // sum(counts) == N == 8192
    float ncs = (ncs0v + 1e-5f) / (nsum + KEPS) * nsum;
    if (lane == 0) out_ncs[k] = ncs;
    size_t base = (size_t)k * 256 + lane * 4;
    float4 e4 = *(const float4*)(ema + base);
    float r0 = e4.x * 0.99f + C1 * dwv.x;
    float r1 = e4.y * 0.99f + C1 * dwv.y;
    float r2 = e4.z * 0.99f + C1 * dwv.z;
    float r3 = e4.w * 0.99f + C1 * dwv.w;
    out_ema[base + 0] = r0; out_ema[base + 1] = r1; out_ema[base + 2] = r2; out_ema[base + 3] = r3;
    out_emb[base + 0] = r0 / ncs; out_emb[base + 1] = r1 / ncs;
    out_emb[base + 2] = r2 / ncs; out_emb[base + 3] = r3 / ncs;
    if (blockIdx.x == 0 && threadIdx.x == 0) {
        float m = scal[0] * (1.0f / 2097152.0f);
        out_loss[0] = m + 0.25f * m;
    }
}

extern "C" void kernel_launch(void* const* d_in, const int* in_sizes, int n_in,
                              void* d_out, int out_size, void* d_ws, size_t ws_size,
                              hipStream_t stream) {
    const float* z   = (const float*)d_in[0];
    const float* emb = (const float*)d_in[1];
    const float* cs  = (const float*)d_in[2];
    const float* ema = (const float*)d_in[3];
    float* out = (float*)d_out;
    float* wsf = (float*)d_ws;

    float* asq  = wsf + OFF_ASQ;
    float* bsq  = wsf + OFF_BSQ;
    int*   cnt  = (int*)(wsf + OFF_CNT);
    int*   head = (int*)(wsf + OFF_HEAD);
    float* scal = wsf + OFF_SCAL;
    int*   nxt  = (int*)(wsf + OFF_NXT);
    float* zf32 = wsf + OFF_ZF;
    _Float16* Bh = (_Float16*)(wsf + OFF_BH);

    float* out_zq   = out;                 // [2097152]
    float* out_loss = out + 2097152;       // [1]
    float* out_idx  = out + 2097153;       // [8192]
    float* out_ncs  = out + 2105345;       // [8192]
    float* out_ema  = out + 2113537;       // [2097152]
    float* out_emb  = out + 4210689;       // [2097152]

    // scratch aliased into dead d_out regions:
    unsigned* pdk = (unsigned*)out;                      // out_zq region (4 of 8 MB), dead until k_zq
    _Float16* Ah = (_Float16*)(out + 2113540);           // 4 MB, 16B-aligned, ema region (dead till k_fin writes)
    _Float16* Am = (_Float16*)(out + 2113540 + 1048576); // 4 MB (tail 3 floats into out_emb region)
    _Float16* Bm = (_Float16*)(out + 4210692);           // 4 MB, 16B-aligned, out_emb region (dead till k_fin)

    k_prep<<<2608, 256, 0, stream>>>(z, emb, asq, bsq, Bh, Bm, Ah, Am, zf32, wsf + OFF_CNT);
    k_main<<<dim3(64, 64), 512, 0, stream>>>(Ah, Am, Bh, Bm, asq, bsq, pdk);
    k_red<<<2048, 256, 0, stream>>>(pdk, cs, out_idx, cnt, head, nxt, scal);
    k_zq<<<dim3(128, 4), 256, 0, stream>>>(z, emb, out_idx, out_zq, scal);
    k_fin<<<2048, 256, 0, stream>>>(cs, ema, head, nxt, zf32, scal, cnt, out_ncs, out_ema, out_emb, out_loss);
}

// Round 7
// 243.326 us; speedup vs baseline: 2.0448x; 1.0167x over previous
//
#include <hip/hip_runtime.h>

#define CHW 262144   // C*H*W = 256*32*32
#define HWD 1024     // H*W

typedef _Float16 v8h __attribute__((ext_vector_type(8)));
typedef _Float16 v4h __attribute__((ext_vector_type(4)));
typedef float    v4f __attribute__((ext_vector_type(4)));

// ws layout (float offsets), total 4235272 floats = 16.9 MB (ws >= 21.1 MB proven r1)
static const unsigned OFF_ASQ  = 0;        // ||z_n||^2 [8192]
static const unsigned OFF_BSQ  = 8192;     // ||e_k||^2 [8192]
static const unsigned OFF_CNT  = 16384;    // counts (int, zeroed by k_prep) [8192]
static const unsigned OFF_HEAD = 24576;    // list heads, n+1, 0=end (int, zeroed) [8192]
static const unsigned OFF_SCAL = 32768;    // [0]=loss_sum [1]=sum(cs) (zeroed) [8]
static const unsigned OFF_NXT  = 32776;    // list next (int) [8192]
static const unsigned OFF_ZF   = 40968;    // zf32 [n][c] [2097152]
static const unsigned OFF_BH   = 2138120;  // Bh fp16 [8192*256] (1048576 floats, 16B-aligned)
static const unsigned OFF_PDK  = 3186696;  // u32 keys [8192][128] block-contiguous [1048576]

#define GLL(g, l) __builtin_amdgcn_global_load_lds( \
    (const __attribute__((address_space(1))) void*)(g), \
    (__attribute__((address_space(3))) void*)(l), 16, 0, 0)

// ---- stage 1: ||z||^2 | emb->bsq+fp16 split | z transpose+split+zf32 | zero cnt/head/scal ----
__global__ __launch_bounds__(256) void k_prep(const float* __restrict__ z,
        const float* __restrict__ emb, float* __restrict__ asq, float* __restrict__ bsq,
        _Float16* __restrict__ Bh, _Float16* __restrict__ Bm,
        _Float16* __restrict__ Ah, _Float16* __restrict__ Am,
        float* __restrict__ zf32, float* __restrict__ zerobase) {
    int bx = blockIdx.x;
    int t = threadIdx.x;
    if (bx < 32) {
        // ||z_n||^2 — EXACT sequential 256-chain (bits feed the argmin; do not reorder)
        int n = bx * 256 + t;
        const float* p = z + (size_t)(n >> 10) * CHW + (n & 1023);
        float s = 0.f;
        #pragma unroll 8
        for (int c = 0; c < 256; ++c) { float v = p[(size_t)c << 10]; s = fmaf(v, v, s); }
        asq[n] = s;
    } else if (bx < 2080) {
        int w = (bx - 32) * 4 + (t >> 6);
        int lane = t & 63;
        float4 v = *(const float4*)(emb + (size_t)w * 256 + lane * 4);
        float s = v.x * v.x;
        s = fmaf(v.y, v.y, s); s = fmaf(v.z, v.z, s); s = fmaf(v.w, v.w, s);
        #pragma unroll
        for (int m = 1; m < 64; m <<= 1) s += __shfl_xor(s, m, 64);
        if (lane == 0) bsq[w] = s;
        float e0 = v.x * 8192.0f, e1 = v.y * 8192.0f, e2 = v.z * 8192.0f, e3 = v.w * 8192.0f;
        _Float16 h0 = (_Float16)e0, h1 = (_Float16)e1, h2 = (_Float16)e2, h3 = (_Float16)e3;
        v4h hv = {h0, h1, h2, h3};
        v4h mv = {(_Float16)((e0 - (float)h0) * 2048.0f),
                  (_Float16)((e1 - (float)h1) * 2048.0f),
                  (_Float16)((e2 - (float)h2) * 2048.0f),
                  (_Float16)((e3 - (float)h3) * 2048.0f)};
        *(v4h*)(Bh + (size_t)w * 256 + lane * 4) = hv;
        *(v4h*)(Bm + (size_t)w * 256 + lane * 4) = mv;
    } else if (bx < 2592) {
        __shared__ float s[64][65];
        int blk = bx - 2080;
        int hw0 = (blk & 15) * 64;
        int c0  = ((blk >> 4) & 3) * 64;
        int b   = blk >> 6;
        #pragma unroll
        for (int ii = 0; ii < 16; ++ii) {
            int e = t + ii * 256;
            int c = e >> 6, x = e & 63;
            s[c][x] = z[(size_t)b * CHW + (size_t)(c0 + c) * HWD + hw0 + x];
        }
        __syncthreads();
        int n = t & 63, cseg = (t >> 6) * 16;
        _Float16 hbuf[16], mbuf[16];
        float fbuf[16];
        #pragma unroll
        for (int j = 0; j < 16; ++j) {
            float v = s[cseg + j][n];
            _Float16 h = (_Float16)v;
            float r = v - (float)h;
            fbuf[j] = v;
            hbuf[j] = h;
            mbuf[j] = (_Float16)(r * 2048.0f);
        }
        size_t off = ((size_t)b * 1024 + hw0 + n) * 256 + c0 + cseg;
        *(v8h*)(Ah + off)     = *(v8h*)(hbuf);
        *(v8h*)(Ah + off + 8) = *(v8h*)(hbuf + 8);
        *(v8h*)(Am + off)     = *(v8h*)(mbuf);
        *(v8h*)(Am + off + 8) = *(v8h*)(mbuf + 8);
        #pragma unroll
        for (int q = 0; q < 4; ++q)
            *(float4*)(zf32 + off + q * 4) = *(float4*)(fbuf + q * 4);
    } else {
        // zero cnt[8192] + head[8192] (+ scal[8])
        int idx = (bx - 2592) * 1024 + t * 4;
        *(float4*)(zerobase + idx) = (float4){0.f, 0.f, 0.f, 0.f};
        if (bx == 2607 && t == 0) {
            *(float4*)(zerobase + 16384) = (float4){0.f, 0.f, 0.f, 0.f};
            *(float4*)(zerobase + 16388) = (float4){0.f, 0.f, 0.f, 0.f};
        }
    }
}

// ---- main: 128x128 tile, 512 threads (8 waves of 32x64), dbuf LDS, 3-product fp16x2 ----
// FROZEN numerics/schedule since r6 (per-element MFMA chains + fl-epilogue bit-identical).
__global__ __launch_bounds__(512, 4) void k_main(
        const _Float16* __restrict__ Ah, const _Float16* __restrict__ Am,
        const _Float16* __restrict__ Bh, const _Float16* __restrict__ Bm,
        const float* __restrict__ asq, const float* __restrict__ bsq,
        unsigned* __restrict__ pdk) {
    __shared__ _Float16 lds[32768];  // 64 KB: 2 buf x (4 mats x [128 rows x 32 halves]), XOR-swizzled
    const int kt = blockIdx.x, nt = blockIdx.y;
    const int n0 = nt * 128, k0 = kt * 128;
    const int t = threadIdx.x;
    const int lane = t & 63, w = t >> 6;       // w in [0,8)
    const int wrow = w >> 1, wcol = w & 1;     // wave tile: rows wrow*32, cols wcol*64
    const int lm = lane & 15, quad = lane >> 4;

    v4f acc1[2][4], acc2[2][4];
    #pragma unroll
    for (int i = 0; i < 2; ++i)
        #pragma unroll
        for (int j = 0; j < 4; ++j) { acc1[i][j] = (v4f){0.f,0.f,0.f,0.f}; acc2[i][j] = (v4f){0.f,0.f,0.f,0.f}; }

    const int row0 = t >> 2;                   // [0,128)
    const int c40 = (t & 3) ^ ((row0 >> 1) & 3);
    const char* gA  = (const char*)Ah + (size_t)(n0 + row0) * 512 + c40 * 16;
    const char* gAm = (const char*)Am + (size_t)(n0 + row0) * 512 + c40 * 16;
    const char* gB  = (const char*)Bh + (size_t)(k0 + row0) * 512 + c40 * 16;
    const char* gBm = (const char*)Bm + (size_t)(k0 + row0) * 512 + c40 * 16;

    int sa[2], sb[4];
    #pragma unroll
    for (int i = 0; i < 2; ++i) {
        int mr = wrow * 32 + i * 16 + lm;
        sa[i] = mr * 32 + ((quad ^ ((mr >> 1) & 3)) * 8);
    }
    #pragma unroll
    for (int j = 0; j < 4; ++j) {
        int nr = wcol * 64 + j * 16 + lm;
        sb[j] = nr * 32 + ((quad ^ ((nr >> 1) & 3)) * 8);
    }

    auto stage = [&](int cb, int buf) {
        const size_t co = (size_t)cb * 64;      // 32 halves per cb
        _Float16* l = lds + buf * 16384 + t * 8;  // lane-linear 16B dest per wave
        GLL(gA + co,  l);
        GLL(gAm + co, l + 4096);
        GLL(gB + co,  l + 8192);
        GLL(gBm + co, l + 12288);
    };

    stage(0, 0);
    for (int cb = 0; cb < 8; ++cb) {
        __syncthreads();
        if (cb < 7) stage(cb + 1, (cb + 1) & 1);
        const _Float16* L = lds + (cb & 1) * 16384;

        v8h fa[2], fam[2];
        #pragma unroll
        for (int i = 0; i < 2; ++i) {
            fa[i]  = *(const v8h*)(L + sa[i]);
            fam[i] = *(const v8h*)(L + 4096 + sa[i]);
        }
        #pragma unroll
        for (int jh = 0; jh < 2; ++jh) {       // j in halves to cap frag registers
            v8h fb0  = *(const v8h*)(L + 8192 + sb[jh * 2]);
            v8h fb1  = *(const v8h*)(L + 8192 + sb[jh * 2 + 1]);
            v8h fbm0 = *(const v8h*)(L + 12288 + sb[jh * 2]);
            v8h fbm1 = *(const v8h*)(L + 12288 + sb[jh * 2 + 1]);
            #pragma unroll
            for (int i = 0; i < 2; ++i) {
                int j0 = jh * 2;
                acc1[i][j0]     = __builtin_amdgcn_mfma_f32_16x16x32_f16(fa[i],  fb0,  acc1[i][j0], 0, 0, 0);
                acc2[i][j0]     = __builtin_amdgcn_mfma_f32_16x16x32_f16(fa[i],  fbm0, acc2[i][j0], 0, 0, 0);
                acc2[i][j0]     = __builtin_amdgcn_mfma_f32_16x16x32_f16(fam[i], fb0,  acc2[i][j0], 0, 0, 0);
                acc1[i][j0 + 1] = __builtin_amdgcn_mfma_f32_16x16x32_f16(fa[i],  fb1,  acc1[i][j0 + 1], 0, 0, 0);
                acc2[i][j0 + 1] = __builtin_amdgcn_mfma_f32_16x16x32_f16(fa[i],  fbm1, acc2[i][j0 + 1], 0, 0, 0);
                acc2[i][j0 + 1] = __builtin_amdgcn_mfma_f32_16x16x32_f16(fam[i], fb1,  acc2[i][j0 + 1], 0, 0, 0);
            }
        }
    }

    // epilogue: d = fl(fl(a+b) - 2*S); u32 key = ((d - a)*2^16 + 32768)<<13 | k  (exact ints)
    // store layout: pdk[(nt*128 + kt*2 + wcol)*128 + mm] — block-contiguous 512B runs
    float bvv[4];
    #pragma unroll
    for (int j = 0; j < 4; ++j) bvv[j] = bsq[k0 + wcol * 64 + j * 16 + lm];
    unsigned* prow = pdk + ((size_t)(nt * 128 + kt * 2 + wcol) << 7);
    #pragma unroll
    for (int i = 0; i < 2; ++i) {
        #pragma unroll
        for (int r = 0; r < 4; ++r) {
            int mm = wrow * 32 + i * 16 + quad * 4 + r;
            float av_ = asq[n0 + mm];
            unsigned best = 0xFFFFFFFFu;
            #pragma unroll
            for (int j = 0; j < 4; ++j) {
                float S = fmaf(acc2[i][j][r], 4.8828125e-4f, acc1[i][j][r]) * 1.220703125e-4f;
                float dd = (av_ + bvv[j]) - 2.0f * S;      // SAME BITS as rounds 3/5/6
                float gv = dd - av_;                        // exact (Sterbenz)
                int mi = (int)(gv * 65536.0f) + 32768;      // exact integer
                int col = k0 + wcol * 64 + j * 16 + lm;
                unsigned key = ((unsigned)mi << 13) | (unsigned)col;
                best = key < best ? key : best;
            }
            #pragma unroll
            for (int xm = 1; xm < 16; xm <<= 1) {           // reduce over lm within each quad
                unsigned o = __shfl_xor(best, xm, 64);
                best = o < best ? o : best;
            }
            if (lm == 0) prow[mm] = best;
        }
    }
}

// ---- fused: per-block key reduce -> idx | lists/histogram/cs-sum (y==0) | z_q + loss ----
__global__ __launch_bounds__(256) void k_zqr(const unsigned* __restrict__ pdk,
        const float* __restrict__ z, const float* __restrict__ emb, const float* __restrict__ cs,
        float* __restrict__ out_idx, int* __restrict__ cnt,
        int* __restrict__ head, int* __restrict__ nxt,
        float* __restrict__ out_zq, float* __restrict__ scal) {
    const int bx = blockIdx.x, by = blockIdx.y;
    const int n0 = bx * 64, c00 = by * 64;
    const int lane = threadIdx.x & 63, g = threadIdx.x >> 6;
    const int nt = bx >> 1, mb = (bx & 1) * 64;

    // phase 1: min over 128 j-rows for the block's 64 n; lane l ends with n0+l's key
    unsigned mn = 0xFFFFFFFFu;
    const unsigned* base = pdk + (((size_t)nt * 128 + g * 32) << 7) + mb + lane;
    #pragma unroll 8
    for (int jj = 0; jj < 32; ++jj) {
        unsigned key = base[jj << 7];          // coalesced 256B run per j
        mn = key < mn ? key : mn;
    }
    __shared__ unsigned part[4][64];
    part[g][lane] = mn;
    __syncthreads();
    unsigned k0v = part[0][lane], k1v = part[1][lane];
    unsigned k2v = part[2][lane], k3v = part[3][lane];
    unsigned f01 = k0v < k1v ? k0v : k1v;
    unsigned f23 = k2v < k3v ? k2v : k3v;
    unsigned fkey = f01 < f23 ? f01 : f23;
    int idxn = (int)(fkey & 8191u);
    int n = n0 + lane;

    if (by == 0) {
        if (g == 0) {
            out_idx[n] = (float)idxn;
            atomicAdd(cnt + idxn, 1);
            int old = atomicExch(head + idxn, n + 1);   // 0 = end-of-list
            nxt[n] = old;
        } else if (g == 1) {
            float cv = cs[n];
            #pragma unroll
            for (int m = 1; m < 64; m <<= 1) cv += __shfl_xor(cv, m, 64);
            if (lane == 0) atomicAdd(scal + 1, cv);
        }
    }

    // phase 2: z_q gather + straight-through write + loss
    int b = n >> 10, hw = n & 1023;
    const float* zr = z + (size_t)b * CHW + hw;
    const float* er = emb + (size_t)idxn * 256;
    float* oz = out_zq + (size_t)b * CHW + hw;
    float ls = 0.f;
    #pragma unroll
    for (int q = 0; q < 4; ++q) {
        int c = c00 + g * 16 + q * 4;
        float4 e4 = *(const float4*)(er + c);
        float ev[4] = {e4.x, e4.y, e4.z, e4.w};
        #pragma unroll
        for (int r = 0; r < 4; ++r) {
            float zp = zr[(size_t)(c + r) << 10];
            float dif = ev[r] - zp;
            oz[(size_t)(c + r) << 10] = zp + dif;
            ls = fmaf(dif, dif, ls);
        }
    }
    #pragma unroll
    for (int m = 1; m < 64; m <<= 1) ls += __shfl_xor(ls, m, 64);
    __shared__ float red[4];
    if (lane == 0) red[g] = ls;
    __syncthreads();
    if (threadIdx.x == 0) atomicAdd(scal, red[0] + red[1] + red[2] + red[3]);
}

// ---- finalize: list-walk dw (in regs), new_cs, new_ema_w, new_embedding, loss ----
__global__ __launch_bounds__(256) void k_fin(const float* __restrict__ cs, const float* __restrict__ ema,
        const int* __restrict__ head, const int* __restrict__ nxt, const float* __restrict__ zf32,
        const float* __restrict__ scal, const int* __restrict__ cnt,
        float* __restrict__ out_ncs, float* __restrict__ out_ema,
        float* __restrict__ out_emb, float* __restrict__ out_loss) {
    int k = blockIdx.x * 4 + (threadIdx.x >> 6);
    int lane = threadIdx.x & 63;
    // dw[k][:] = sum of zf rows assigned to k (wave-uniform list walk, no atomics)
    float4 dwv = {0.f, 0.f, 0.f, 0.f};
    int cur = head[k];
    while (cur) {
        int n = cur - 1;
        float4 v = *(const float4*)(zf32 + (size_t)n * 256 + lane * 4);
        dwv.x += v.x; dwv.y += v.y; dwv.z += v.z; dwv.w += v.w;
        cur = nxt[n];
    }
    const float C1 = (float)(1.0 - 0.99);
    const float KEPS = (float)(8192 * 1e-5);
    float ncs0v = cs[k] * 0.99f + C1 * (float)cnt[k];
    float nsum = 0.99f * scal[1] + C1 * 8192.0f;   // sum(counts) == N == 8192
    float ncs = (ncs0v + 1e-5f) / (nsum + KEPS) * nsum;
    if (lane == 0) out_ncs[k] = ncs;
    size_t base = (size_t)k * 256 + lane * 4;
    float4 e4 = *(const float4*)(ema + base);
    float r0 = e4.x * 0.99f + C1 * dwv.x;
    float r1 = e4.y * 0.99f + C1 * dwv.y;
    float r2 = e4.z * 0.99f + C1 * dwv.z;
    float r3 = e4.w * 0.99f + C1 * dwv.w;
    out_ema[base + 0] = r0; out_ema[base + 1] = r1; out_ema[base + 2] = r2; out_ema[base + 3] = r3;
    out_emb[base + 0] = r0 / ncs; out_emb[base + 1] = r1 / ncs;
    out_emb[base + 2] = r2 / ncs; out_emb[base + 3] = r3 / ncs;
    if (blockIdx.x == 0 && threadIdx.x == 0) {
        float m = scal[0] * (1.0f / 2097152.0f);
        out_loss[0] = m + 0.25f * m;
    }
}

extern "C" void kernel_launch(void* const* d_in, const int* in_sizes, int n_in,
                              void* d_out, int out_size, void* d_ws, size_t ws_size,
                              hipStream_t stream) {
    const float* z   = (const float*)d_in[0];
    const float* emb = (const float*)d_in[1];
    const float* cs  = (const float*)d_in[2];
    const float* ema = (const float*)d_in[3];
    float* out = (float*)d_out;
    float* wsf = (float*)d_ws;

    float* asq  = wsf + OFF_ASQ;
    float* bsq  = wsf + OFF_BSQ;
    int*   cnt  = (int*)(wsf + OFF_CNT);
    int*   head = (int*)(wsf + OFF_HEAD);
    float* scal = wsf + OFF_SCAL;
    int*   nxt  = (int*)(wsf + OFF_NXT);
    float* zf32 = wsf + OFF_ZF;
    _Float16* Bh = (_Float16*)(wsf + OFF_BH);
    unsigned* pdk = (unsigned*)(wsf + OFF_PDK);

    float* out_zq   = out;                 // [2097152]
    float* out_loss = out + 2097152;       // [1]
    float* out_idx  = out + 2097153;       // [8192]
    float* out_ncs  = out + 2105345;       // [8192]
    float* out_ema  = out + 2113537;       // [2097152]
    float* out_emb  = out + 4210689;       // [2097152]

    // scratch aliased into dead d_out regions (all dead until k_fin's writes):
    _Float16* Ah = (_Float16*)(out + 2113540);           // 4 MB, 16B-aligned, ema region
    _Float16* Am = (_Float16*)(out + 2113540 + 1048576); // 4 MB (tail 3 floats into out_emb region)
    _Float16* Bm = (_Float16*)(out + 4210692);           // 4 MB, 16B-aligned, out_emb region

    k_prep<<<2608, 256, 0, stream>>>(z, emb, asq, bsq, Bh, Bm, Ah, Am, zf32, wsf + OFF_CNT);
    k_main<<<dim3(64, 64), 512, 0, stream>>>(Ah, Am, Bh, Bm, asq, bsq, pdk);
    k_zqr<<<dim3(128, 4), 256, 0, stream>>>(pdk, z, emb, cs, out_idx, cnt, head, nxt, out_zq, scal);
    k_fin<<<2048, 256, 0, stream>>>(cs, ema, head, nxt, zf32, scal, cnt, out_ncs, out_ema, out_emb, out_loss);
}